// Round 13
// baseline (364.017 us; speedup 1.0000x reference)
//
#include <hip/hip_runtime.h>

#define NTIPS 512
#define DIM   510                     // internal nodes = ntips - 2
#define TOTAL 1022
#define BS    64
#define ITERS 50
#define SLABF 8                       // features per workgroup slab
#define NSLAB 64                      // slabs per tree
#define NWG   (BS * NSLAB)            // 4096 workgroups
#define NPART ((size_t)ITERS * BS * NSLAB)

#define XSECB   (DIM * SLABF * 4)     // 16320 B evolving X per buffer (f32)
#define CONSTB  XSECB                 // const section byte base: 8 one-hot + 1 zero
#define XF32    (DIM * SLABF + 9 * SLABF)   // 4152 f32 per buffer

typedef unsigned short u16;
typedef unsigned int   u32;

// bf16 RNE helpers — bit-identical to validated R6..R12 arithmetic
__device__ __forceinline__ u16 f2bf(float x) {
    u32 u = __float_as_uint(x);
    return (u16)((u + 0x7FFFu + ((u >> 16) & 1u)) >> 16);
}
__device__ __forceinline__ float bf2f(u16 h) { return __uint_as_float(((u32)h) << 16); }
__device__ __forceinline__ float bflo(u32 p) { return __uint_as_float(p << 16); }
__device__ __forceinline__ float bfhi(u32 p) { return __uint_as_float(p & 0xFFFF0000u); }

#if defined(__has_builtin)
#  if __has_builtin(__builtin_amdgcn_cvt_pk_bf16_f32)
#    define HAVE_PKBF 1
#  endif
#endif
#ifdef HAVE_PKBF
typedef __bf16 bf16x2 __attribute__((ext_vector_type(2)));
__device__ __forceinline__ u32 pkbf(float a, float b) {   // lo=a, hi=b, RNE
    bf16x2 r = __builtin_amdgcn_cvt_pk_bf16_f32(a, b);
    return __builtin_bit_cast(u32, r);
}
#else
__device__ __forceinline__ u32 pkbf(float a, float b) {
    return (u32)f2bf(a) | ((u32)f2bf(b) << 16);
}
#endif

// exact f32 RN division by 3 (correctly rounded via double) — validated
__device__ __forceinline__ float div3(float x) {
    return (float)((double)x * (1.0 / 3.0));
}

// packed f32 add: two independent IEEE-RN adds — element-wise bit-identical
__device__ __forceinline__ float2 pk_add(float2 a, float2 b) {
    float2 d;
    asm("v_pk_add_f32 %0, %1, %2" : "=v"(d) : "v"(a), "v"(b));
    return d;
}

// per-thread byte offsets: every neighbor -> X row / one-hot const / zero const
__device__ __forceinline__ void make_offsets(const int* __restrict__ edge,
        int b, int sl, int rg, int qh, int nr, u32 offA[4][3], u32 rowo[4]) {
    #pragma unroll
    for (int k = 0; k < 4; ++k) if (k < nr) {
        const int i = rg + 128 * k;
        rowo[k] = (u32)(i * 32 + qh * 16);
        const int* ep = edge + ((size_t)b * TOTAL + NTIPS + i) * 3;
        #pragma unroll
        for (int t = 0; t < 3; ++t) {
            const int e = ep[t];
            u32 off;
            if (e >= NTIPS)          off = (u32)((e - NTIPS) * 32);
            else if ((e >> 3) == sl) off = (u32)(CONSTB + (e & 7) * 32);
            else                     off = (u32)(CONSTB + 8 * 32);   // zero row
            offA[k][t] = off + (u32)(qh * 16);
        }
    }
}

// one quad update from 3 gathered f32 quads (bf16-exact values):
// per element ((g0+g1)+g2) in f32 RN (packed), exact /3, bf16-round
__device__ __forceinline__ void quad_step(const float4 g0, const float4 g1,
                                          const float4 g2, float nf[4]) {
    float2 s0 = pk_add(make_float2(g0.x, g0.y), make_float2(g1.x, g1.y));
    float2 s1 = pk_add(make_float2(g0.z, g0.w), make_float2(g1.z, g1.w));
    s0 = pk_add(s0, make_float2(g2.x, g2.y));
    s1 = pk_add(s1, make_float2(g2.z, g2.w));
    const u32 u01 = pkbf(div3(s0.x), div3(s0.y));
    const u32 u23 = pkbf(div3(s1.x), div3(s1.y));
    nf[0] = bflo(u01); nf[1] = bfhi(u01);
    nf[2] = bflo(u23); nf[3] = bfhi(u23);
}

__device__ __forceinline__ void init_consts(float* XA, float* XB, int tid) {
    for (int j = tid; j < 9 * SLABF; j += 256) {
        const float v = ((j >> 3) == (j & 7) && (j >> 3) < 8) ? 1.0f : 0.0f;
        XA[DIM * SLABF + j] = v;
        XB[DIM * SLABF + j] = v;
    }
}

// ---------------------------------------------------------------------------
// chunk<W>: steps sBeg+1 .. sBeg+W, fully unrolled (static LDS bases, dacc[W]
// in registers, single deferred reduction). Snapshot X_{sBeg+W} to snapOut.
// ---------------------------------------------------------------------------
template <int W>
__global__ __launch_bounds__(256, 4) void chunk_kernel(
        const int* __restrict__ edge, float* __restrict__ partials,
        int* __restrict__ ctrl, const u16* __restrict__ snapIn,
        u16* __restrict__ snapOut, int q, int sBeg) {
    if (q >= 2 && ctrl[2] != 0) return;          // converged: skip

    __shared__ float XA[XF32], XB[XF32];
    __shared__ float redL[W][4];

    const int wg = blockIdx.x, b = wg >> 6, sl = wg & 63;
    const int tid = threadIdx.x, rg = tid >> 1, qh = tid & 1;
    const int nr = (rg < 126) ? 4 : 3;

    if (q == 1 && wg == 0 && tid == 0) ctrl[2] = 0;   // clear poisoned flag

    u32 offA[4][3], rowo[4];
    make_offsets(edge, b, sl, rg, qh, nr, offA, rowo);

    float oldf[4][4];
    if (q == 1) {
        for (int j = tid; j < DIM * SLABF; j += 256) XA[j] = 1.0f / 512.0f;
        #pragma unroll
        for (int k = 0; k < 4; ++k)
            #pragma unroll
            for (int j = 0; j < 4; ++j) oldf[k][j] = 1.0f / 512.0f;
    } else {
        #pragma unroll
        for (int k = 0; k < 4; ++k) if (k < nr) {
            const int i = rg + 128 * k;
            const ushort4 s4 = *reinterpret_cast<const ushort4*>(
                snapIn + ((size_t)b * DIM + i) * NTIPS + sl * SLABF + qh * 4);
            float4 f;
            f.x = bf2f(s4.x); f.y = bf2f(s4.y);
            f.z = bf2f(s4.z); f.w = bf2f(s4.w);
            *reinterpret_cast<float4*>((char*)XA + rowo[k]) = f;
            oldf[k][0] = f.x; oldf[k][1] = f.y;
            oldf[k][2] = f.z; oldf[k][3] = f.w;
        }
    }
    init_consts(XA, XB, tid);
    __syncthreads();

    float dacc[W];
    #pragma unroll
    for (int u = 0; u < W; ++u) {
        const float* src = (u & 1) ? XB : XA;    // compile-time after unroll
        float*       dst = (u & 1) ? XA : XB;
        float da = 0.f;
        #pragma unroll
        for (int k = 0; k < 4; ++k) if (k < nr) {
            const float4 g0 = *reinterpret_cast<const float4*>(
                (const char*)src + offA[k][0]);
            const float4 g1 = *reinterpret_cast<const float4*>(
                (const char*)src + offA[k][1]);
            const float4 g2 = *reinterpret_cast<const float4*>(
                (const char*)src + offA[k][2]);
            float nf[4];
            quad_step(g0, g1, g2, nf);
            *reinterpret_cast<float4*>((char*)dst + rowo[k]) =
                make_float4(nf[0], nf[1], nf[2], nf[3]);
            const u32 d01 = pkbf(nf[0] - oldf[k][0], nf[1] - oldf[k][1]);
            const u32 d23 = pkbf(nf[2] - oldf[k][2], nf[3] - oldf[k][3]);
            da += fabsf(bflo(d01));
            da += fabsf(bfhi(d01));
            da += fabsf(bflo(d23));
            da += fabsf(bfhi(d23));
            oldf[k][0] = nf[0]; oldf[k][1] = nf[1];
            oldf[k][2] = nf[2]; oldf[k][3] = nf[3];
        }
        dacc[u] = da;
        __syncthreads();                         // Jacobi barrier
    }

    // deferred reductions (independent -> ILP across W shfl chains)
    const int lane = tid & 63, wv = tid >> 6;
    #pragma unroll
    for (int u = 0; u < W; ++u) {
        float v = dacc[u];
        #pragma unroll
        for (int off = 32; off > 0; off >>= 1) v += __shfl_down(v, off);
        if (lane == 0) redL[u][wv] = v;
    }
    __syncthreads();
    if (tid < W) {
        const float dtot = ((redL[tid][0] + redL[tid][1])
                            + redL[tid][2]) + redL[tid][3];
        partials[(size_t)(sBeg + tid) * (BS * NSLAB) + b * NSLAB + sl] = dtot;
    }

    // snapshot X_{sBeg+W} (buffer XB iff W odd)
    const float* fin = (W & 1) ? XB : XA;
    #pragma unroll
    for (int k = 0; k < 4; ++k) if (k < nr) {
        const int i = rg + 128 * k;
        const float4 f = *reinterpret_cast<const float4*>(
            (const char*)fin + rowo[k]);
        uint2 pk; pk.x = pkbf(f.x, f.y); pk.y = pkbf(f.z, f.w);
        *reinterpret_cast<uint2*>(
            snapOut + ((size_t)b * DIM + i) * NTIPS + sl * SLABF + qh * 4) = pk;
    }
}

// ---------------------------------------------------------------------------
// findS: validated decision procedure. Sets {S, c, found, slot} where c is the
// largest chunk-end < S from {0,5,10,15,20,30,40}; slot = parity of c's chunk.
// ---------------------------------------------------------------------------
__global__ void findS_kernel(const float* __restrict__ partials,
                             int* __restrict__ ctrl, int smax) {
    if (ctrl[2] != 0) return;
    const int lane = threadIdx.x;                // 64 lanes = trees
    const float tol_bf = bf2f(f2bf(1e-5f));
    int S = -1;
    for (int s = 1; s <= smax; ++s) {
        const float* p = partials + (size_t)(s - 1) * (BS * NSLAB) + lane * NSLAB;
        float t = 0.f;
        #pragma unroll
        for (int k = 0; k < NSLAB; ++k) t += p[k];
        const float lnorm = bf2f(f2bf(t / 261120.0f));
        if (__ballot(lnorm > tol_bf) == 0ULL) { S = s; break; }
    }
    if (S < 0 && smax == ITERS) S = ITERS;       // MAX_ITERS cap
    if (lane == 0 && S > 0) {
        const int ends[8] = {0, 5, 10, 15, 20, 30, 40, 50};
        int j = 0;
        for (int t = 1; t < 8; ++t) if (ends[t] < S) j = t;
        ctrl[0] = S;
        ctrl[1] = ends[j];                       // checkpoint c
        ctrl[3] = j & 1;                         // 1 -> snapD, 0 -> snapW
        ctrl[2] = 1;
    }
}

// ---------------------------------------------------------------------------
// phaseC: resume from X_c, run S-c (<=10) steps (no delta), write bf16 X_S.
// ---------------------------------------------------------------------------
__global__ __launch_bounds__(256, 4) void phaseC_kernel(
        const int* __restrict__ edge, const int* __restrict__ ctrl,
        const u16* __restrict__ snapD, const u16* __restrict__ snapW,
        u16* __restrict__ finalX) {
    __shared__ float XA[XF32], XB[XF32];

    const int wg = blockIdx.x, b = wg >> 6, sl = wg & 63;
    const int tid = threadIdx.x, rg = tid >> 1, qh = tid & 1;
    const int nr = (rg < 126) ? 4 : 3;

    u32 offA[4][3], rowo[4];
    make_offsets(edge, b, sl, rg, qh, nr, offA, rowo);

    const int S = ctrl[0], c = ctrl[1];
    if (c == 0) {
        for (int j = tid; j < DIM * SLABF; j += 256) XA[j] = 1.0f / 512.0f;
    } else {
        const u16* snap = ctrl[3] ? snapD : snapW;
        #pragma unroll
        for (int k = 0; k < 4; ++k) if (k < nr) {
            const int i = rg + 128 * k;
            const ushort4 s4 = *reinterpret_cast<const ushort4*>(
                snap + ((size_t)b * DIM + i) * NTIPS + sl * SLABF + qh * 4);
            float4 f;
            f.x = bf2f(s4.x); f.y = bf2f(s4.y);
            f.z = bf2f(s4.z); f.w = bf2f(s4.w);
            *reinterpret_cast<float4*>((char*)XA + rowo[k]) = f;
        }
    }
    init_consts(XA, XB, tid);
    __syncthreads();

    const int T = S - c;                         // 1..10
    for (int t = 1; t <= T; ++t) {
        const float* src = (t & 1) ? XA : XB;
        float*       dst = (t & 1) ? XB : XA;
        #pragma unroll
        for (int k = 0; k < 4; ++k) if (k < nr) {
            const float4 g0 = *reinterpret_cast<const float4*>(
                (const char*)src + offA[k][0]);
            const float4 g1 = *reinterpret_cast<const float4*>(
                (const char*)src + offA[k][1]);
            const float4 g2 = *reinterpret_cast<const float4*>(
                (const char*)src + offA[k][2]);
            float nf[4];
            quad_step(g0, g1, g2, nf);
            *reinterpret_cast<float4*>((char*)dst + rowo[k]) =
                make_float4(nf[0], nf[1], nf[2], nf[3]);
        }
        __syncthreads();
    }

    const float* fin = (T & 1) ? XB : XA;
    #pragma unroll
    for (int k = 0; k < 4; ++k) if (k < nr) {
        const int i = rg + 128 * k;
        const float4 f = *reinterpret_cast<const float4*>(
            (const char*)fin + rowo[k]);
        uint2 pk; pk.x = pkbf(f.x, f.y); pk.y = pkbf(f.z, f.w);
        *reinterpret_cast<uint2*>(
            finalX + ((size_t)b * DIM + i) * NTIPS + sl * SLABF + qh * 4) = pk;
    }
}

// ---------------------------------------------------------------------------
// convert: d_out fp32 = [identity ; f32(bf16 finalX)] per batch.
// ---------------------------------------------------------------------------
__global__ __launch_bounds__(64) void convert_kernel(
        const u16* __restrict__ finalX, float* __restrict__ out) {
    const int r = blockIdx.x;                    // 0..1021
    const int b = blockIdx.y;
    const int f0 = threadIdx.x << 3;             // 8 floats per thread
    float4 lo, hi;
    if (r < NTIPS) {
        lo.x = (r == f0 + 0) ? 1.f : 0.f;
        lo.y = (r == f0 + 1) ? 1.f : 0.f;
        lo.z = (r == f0 + 2) ? 1.f : 0.f;
        lo.w = (r == f0 + 3) ? 1.f : 0.f;
        hi.x = (r == f0 + 4) ? 1.f : 0.f;
        hi.y = (r == f0 + 5) ? 1.f : 0.f;
        hi.z = (r == f0 + 6) ? 1.f : 0.f;
        hi.w = (r == f0 + 7) ? 1.f : 0.f;
    } else {
        const u16* row = finalX + ((size_t)b * DIM + (r - NTIPS)) * NTIPS + f0;
        const ushort4 a = *reinterpret_cast<const ushort4*>(row);
        const ushort4 c = *reinterpret_cast<const ushort4*>(row + 4);
        lo.x = bf2f(a.x); lo.y = bf2f(a.y); lo.z = bf2f(a.z); lo.w = bf2f(a.w);
        hi.x = bf2f(c.x); hi.y = bf2f(c.y); hi.z = bf2f(c.z); hi.w = bf2f(c.w);
    }
    float* drow = out + ((size_t)b * TOTAL + r) * NTIPS + f0;
    *reinterpret_cast<float4*>(drow)     = lo;
    *reinterpret_cast<float4*>(drow + 4) = hi;
}

extern "C" void kernel_launch(void* const* d_in, const int* in_sizes, int n_in,
                              void* d_out, int out_size, void* d_ws, size_t ws_size,
                              hipStream_t stream) {
    const int* edge = (const int*)d_in[1];       // (BS, TOTAL, 3) int32
    float* out = (float*)d_out;

    const size_t XB16 = (size_t)BS * DIM * NTIPS;   // 16,711,680 u16
    u16*   snapW = (u16*)d_ws;
    float* partials = (float*)((char*)d_ws + XB16 * sizeof(u16));
    int*   ctrl = (int*)(partials + NPART);
    u16*   snapD = (u16*)d_out;                  // d_out scratch

    const int begs[7] = {0, 5, 10, 15, 20, 30, 40};
    const int ends[7] = {5, 10, 15, 20, 30, 40, 50};
    for (int j = 0; j < 7; ++j) {
        const int q = j + 1;
        u16* snapIn  = ((q - 1) & 1) ? snapD : snapW;   // prev chunk's slot
        u16* snapOut = (q & 1) ? snapD : snapW;
        if (ends[j] - begs[j] == 5)
            chunk_kernel<5><<<NWG, 256, 0, stream>>>(edge, partials, ctrl,
                                                     snapIn, snapOut, q, begs[j]);
        else
            chunk_kernel<10><<<NWG, 256, 0, stream>>>(edge, partials, ctrl,
                                                      snapIn, snapOut, q, begs[j]);
        findS_kernel<<<1, 64, 0, stream>>>(partials, ctrl, ends[j]);
    }
    phaseC_kernel<<<NWG, 256, 0, stream>>>(edge, ctrl, snapD, snapW, snapW);
    convert_kernel<<<dim3(TOTAL, BS), 64, 0, stream>>>(snapW, out);
}